// Round 12
// baseline (218.253 us; speedup 1.0000x reference)
//
#include <hip/hip_runtime.h>
#include <math.h>

// Problem constants (fixed by reference setup_inputs)
#define BATCH 4
#define SEQ   1024
#define DM    1024       // d_model
#define NH    16         // heads
#define DH    64         // head dim
#define BT    (BATCH*SEQ)   // 4096 GEMM rows

typedef _Float16 f16x8 __attribute__((ext_vector_type(8)));
typedef _Float16 f16x4 __attribute__((ext_vector_type(4)));
typedef float    f32x4 __attribute__((ext_vector_type(4)));

// async global->LDS, 16B per lane; LDS dest is wave-uniform base + lane*16
#define GLL16(ldsdst, gsrc) \
  __builtin_amdgcn_global_load_lds((const __attribute__((address_space(1))) void*)(gsrc), \
                                   (__attribute__((address_space(3))) void*)(ldsdst), 16, 0, 0)

// ---------------------------------------------------------------------------
// fp32 -> f16 elementwise (x conversion), float4 -> f16x4
// ---------------------------------------------------------------------------
__global__ __launch_bounds__(256) void cvt_x(const float* __restrict__ x,
                                             _Float16* __restrict__ xh, int nquads)
{
    int i = blockIdx.x * blockDim.x + threadIdx.x;
    for (; i < nquads; i += gridDim.x * blockDim.x) {
        float4 f = ((const float4*)x)[i];
        f16x4 h;
        h[0] = (_Float16)f.x; h[1] = (_Float16)f.y;
        h[2] = (_Float16)f.z; h[3] = (_Float16)f.w;
        ((f16x4*)xh)[i] = h;
    }
}

// ---------------------------------------------------------------------------
// W [1024 k][1024 n] fp32  ->  Wt [1024 n][1024 k] f16   (4 weights, grid.z)
// ---------------------------------------------------------------------------
__global__ __launch_bounds__(256) void cvt_wT(
    const float* __restrict__ W0, const float* __restrict__ W1,
    const float* __restrict__ W2, const float* __restrict__ W3,
    _Float16* __restrict__ T0, _Float16* __restrict__ T1,
    _Float16* __restrict__ T2, _Float16* __restrict__ T3)
{
    __shared__ _Float16 tile[64][72];
    const int z = blockIdx.z;
    const float* W = (z == 0) ? W0 : (z == 1) ? W1 : (z == 2) ? W2 : W3;
    _Float16*    T = (z == 0) ? T0 : (z == 1) ? T1 : (z == 2) ? T2 : T3;
    const int n0 = blockIdx.x * 64;
    const int k0 = blockIdx.y * 64;
    const int tid = threadIdx.x;
#pragma unroll
    for (int p = 0; p < 4; ++p) {
        int r = (tid >> 4) + p * 16;           // k within tile
        int c = (tid & 15) * 4;                // n within tile
        float4 f = *(const float4*)&W[(size_t)(k0 + r) * DM + n0 + c];
        f16x4 h;
        h[0] = (_Float16)f.x; h[1] = (_Float16)f.y;
        h[2] = (_Float16)f.z; h[3] = (_Float16)f.w;
        *(f16x4*)&tile[r][c] = h;
    }
    __syncthreads();
#pragma unroll
    for (int p = 0; p < 2; ++p) {
        int nr = (tid >> 3) + p * 32;          // n within tile
        int kc = (tid & 7) * 8;                // k within tile
        f16x8 vv;
#pragma unroll
        for (int i = 0; i < 8; ++i) vv[i] = tile[kc + i][nr];
        *(f16x8*)&T[(size_t)(n0 + nr) * DM + k0 + kc] = vv;
    }
}

// ---------------------------------------------------------------------------
// f16 MFMA GEMM, m97 structure: 128x128 tile, BK=32, 4 waves, 4x4 16x16x32
// frags per wave, global_load_lds staging (linear LDS), 2-barrier K-loop.
// ---------------------------------------------------------------------------
template<int MODE>
__global__ __launch_bounds__(256) void gemm_mfma(
    const _Float16* __restrict__ A,
    const _Float16* __restrict__ B0, const _Float16* __restrict__ B1,
    const _Float16* __restrict__ B2,
    void* __restrict__ o0, void* __restrict__ o1, void* __restrict__ o2,
    const float* __restrict__ bias)
{
    __shared__ _Float16 As[128 * 32];
    __shared__ _Float16 Bs[128 * 32];

    const int tid = threadIdx.x;
    const int w   = tid >> 6;          // wave 0..3
    const int ln  = tid & 63;
    const int l15 = ln & 15;
    const int lg  = ln >> 4;           // 0..3
    const int wr  = w >> 1;            // wave row quadrant
    const int wc  = w & 1;             // wave col quadrant
    const int which = MODE ? (blockIdx.x >> 3) : 0;     // 0:q 1:k 2:v
    const int nl  = (blockIdx.x & 7) * 128;
    const int m0  = blockIdx.y * 128;

    const _Float16* Bt = (which == 0) ? B0 : (which == 1 ? B1 : B2);

    const int srow = ln >> 2;          // 0..15
    const int scol = (ln & 3) * 8;     // halves
    const _Float16* ga = A  + (size_t)(m0 + w * 32 + srow) * DM + scol;
    const _Float16* gb = Bt + (size_t)(nl + w * 32 + srow) * DM + scol;
    _Float16* la0 = &As[(w * 32 +  0) * 32];
    _Float16* la1 = &As[(w * 32 + 16) * 32];
    _Float16* lb0 = &Bs[(w * 32 +  0) * 32];
    _Float16* lb1 = &Bs[(w * 32 + 16) * 32];

    f32x4 acc[4][4];
#pragma unroll
    for (int i = 0; i < 4; ++i)
#pragma unroll
        for (int j = 0; j < 4; ++j) acc[i][j] = (f32x4){0.f, 0.f, 0.f, 0.f};

    for (int k0 = 0; k0 < DM; k0 += 32) {
        GLL16(la0, ga + k0);
        GLL16(la1, ga + k0 + (size_t)16 * DM);
        GLL16(lb0, gb + k0);
        GLL16(lb1, gb + k0 + (size_t)16 * DM);
        __syncthreads();               // drains vmcnt: tiles staged

        f16x8 af[4], bf[4];
#pragma unroll
        for (int i = 0; i < 4; ++i)
            af[i] = *(const f16x8*)&As[(wr * 64 + i * 16 + l15) * 32 + lg * 8];
#pragma unroll
        for (int j = 0; j < 4; ++j)
            bf[j] = *(const f16x8*)&Bs[(wc * 64 + j * 16 + l15) * 32 + lg * 8];
#pragma unroll
        for (int i = 0; i < 4; ++i)
#pragma unroll
            for (int j = 0; j < 4; ++j)
                acc[i][j] = __builtin_amdgcn_mfma_f32_16x16x32_f16(af[i], bf[j], acc[i][j], 0, 0, 0);
        __syncthreads();               // all reads done before next overwrite
    }

    if (MODE == 1) {
        _Float16* outp = (which == 0) ? (_Float16*)o0
                        : (which == 1) ? (_Float16*)o1 : (_Float16*)o2;
        const float scale = (which == 0) ? 0.015625f : 1.0f;   // Q /= 64
#pragma unroll
        for (int i = 0; i < 4; ++i)
#pragma unroll
            for (int j = 0; j < 4; ++j) {
                int n  = nl + wc * 64 + j * 16 + l15;
                int hh = n >> 6, d = n & 63;
#pragma unroll
                for (int r = 0; r < 4; ++r) {
                    int m  = m0 + wr * 64 + i * 16 + lg * 4 + r;
                    int b_ = m >> 10, t_ = m & 1023;
                    outp[(((size_t)(b_ * NH + hh)) * SEQ + t_) * DH + d] =
                        (_Float16)(acc[i][j][r] * scale);
                }
            }
    } else {
        float* outp = (float*)o0;
#pragma unroll
        for (int i = 0; i < 4; ++i)
#pragma unroll
            for (int j = 0; j < 4; ++j) {
                int n = nl + wc * 64 + j * 16 + l15;
                float bz = bias[n];
#pragma unroll
                for (int r = 0; r < 4; ++r) {
                    int m = m0 + wr * 64 + i * 16 + lg * 4 + r;
                    outp[(size_t)m * DM + n] = acc[i][j][r] + bz;
                }
            }
    }
}

// ---------------------------------------------------------------------------
// V [bh][1024 t][64 d] f16  ->  Vt [bh][64 d][1024 t] f16
// ---------------------------------------------------------------------------
__global__ __launch_bounds__(256) void vtranspose(const _Float16* __restrict__ V,
                                                  _Float16* __restrict__ Vt)
{
    __shared__ _Float16 tile[64][72];
    const int bh = blockIdx.y;
    const int t0 = blockIdx.x * 64;
    const int tid = threadIdx.x;
    const int r = tid >> 3;          // 0..31
    const int c = (tid & 7) * 8;     // 0..56
    const size_t base = (size_t)bh * (SEQ * DH);
#pragma unroll
    for (int p = 0; p < 2; ++p) {
        int row = r + p * 32;
        *(f16x8*)&tile[row][c] = *(const f16x8*)&V[base + (size_t)(t0 + row) * DH + c];
    }
    __syncthreads();
#pragma unroll
    for (int p = 0; p < 2; ++p) {
        int d = r + p * 32;
        f16x8 vv;
#pragma unroll
        for (int i = 0; i < 8; ++i) vv[i] = tile[c + i][d];
        *(f16x8*)&Vt[base + (size_t)d * SEQ + t0 + c] = vv;
    }
}

// ---------------------------------------------------------------------------
// Flash attention, f16 MFMA, swapped-operand + PAIR-AND-SPLIT balance.
// Grid (8 pairs, 64 bh), 512 threads = 8 waves. Wave w = (j = w>>1, s = w&1):
// runs job j (16 q-rows) of qt=pr THEN qt=15-pr, kv-tiles kt ≡ s (mod 2).
// Per-wave work = exactly 9 (s=0) / 8 (s=1) tiles in EVERY block.
// Inner loop is the round-11 swapped-operand form: lane = one q-row,
// m/l/acc lane-local, 4 shuffles/tile total.
// Merge: s=1 stores (acc f16, m, l) to padded LDS; one barrier; s=0 merges
// lane-aligned (c1 = exp(-inf) = 0 handles empty split) and writes.
// ---------------------------------------------------------------------------
__global__ __launch_bounds__(512) void attn_mfma(
    const _Float16* __restrict__ Q,   // [bh][1024][64], pre-scaled by 1/64
    const _Float16* __restrict__ K,   // [bh][1024][64]
    const _Float16* __restrict__ Vt,  // [bh][64][1024]
    const float* __restrict__ rpb,    // [16][1024]
    _Float16* __restrict__ ao)        // [b][t][h*64+d] f16
{
    const int pr  = blockIdx.x;       // 0..7
    const int bh  = blockIdx.y;       // 0..63
    const int b_  = bh >> 4;
    const int h_  = bh & 15;
    const int tid = threadIdx.x;
    const int w   = tid >> 6;         // wave 0..7
    const int j   = w >> 1;           // job 0..3
    const int s   = w & 1;            // kv split
    const int ln  = tid & 63;
    const int l15 = ln & 15;
    const int lg  = ln >> 4;          // 0..3

    __shared__ _Float16 Pb[8][16][72];        // per-wave P buffer (18.4 KB)
    __shared__ _Float16 part[2][4][64][18];   // [ji][j][lane][16 vals] padded (18.4 KB)
    __shared__ float    mlb[2][4][64][3];     // [ji][j][lane][m,l] padded (6 KB)
    __shared__ float    rpb2[1152];           // extended bias table (4.5 KB)

    // stage bias table: entries 0..1023 = rpb[h]/64; 1024..1151 = -1e30
    {
        float2 t = *(const float2*)&rpb[h_ * SEQ + tid * 2];
        t.x *= 0.015625f; t.y *= 0.015625f;
        *(float2*)&rpb2[tid * 2] = t;
        if (tid < 128) rpb2[1024 + tid] = -1e30f;
    }
    __syncthreads();

    const size_t qkb = (size_t)bh * (SEQ * DH);

    // ---- swapped-operand kv loop for one job (qt), split s ----
    auto run = [&](int qt, f32x4 (&accT)[4], float& m, float& l) {
        const int i_ = qt * 64 + j * 16 + l15;     // this lane's q-row
        f16x8 qa0, qa1;
        {
            const _Float16* qp = Q + qkb + (size_t)i_ * DH + lg * 8;
            qa0 = *(const f16x8*)qp;
            qa1 = *(const f16x8*)(qp + 32);
        }
#pragma unroll 1
        for (int kt = s; kt <= qt; kt += 2) {
            const _Float16* kp = K + qkb + (size_t)(kt * 64 + l15) * DH + lg * 8;
            f32x4 sv[4];
#pragma unroll
            for (int st = 0; st < 4; ++st) {
                f16x8 kb0 = *(const f16x8*)(kp + st * 16 * DH);
                f16x8 kb1 = *(const f16x8*)(kp + st * 16 * DH + 32);
                f32x4 z = (f32x4){0.f, 0.f, 0.f, 0.f};
                z = __builtin_amdgcn_mfma_f32_16x16x32_f16(kb0, qa0, z, 0, 0, 0);
                z = __builtin_amdgcn_mfma_f32_16x16x32_f16(kb1, qa1, z, 0, 0, 0);
                sv[st] = z;
            }
            const int bidx = 1023 - i_ + kt * 64 + lg * 4;
            float tmax = -INFINITY;
#pragma unroll
            for (int st = 0; st < 4; ++st)
#pragma unroll
                for (int r = 0; r < 4; ++r) {
                    float v = sv[st][r] + rpb2[bidx + st * 16 + r];
                    sv[st][r] = v;
                    tmax = fmaxf(tmax, v);
                }
            tmax = fmaxf(tmax, __shfl_xor(tmax, 16));
            tmax = fmaxf(tmax, __shfl_xor(tmax, 32));
            float mn   = fmaxf(m, tmax);
            float corr = __expf(m - mn);
            m = mn;
            float ps = 0.f;
#pragma unroll
            for (int st = 0; st < 4; ++st)
#pragma unroll
                for (int r = 0; r < 4; ++r) {
                    float p = __expf(sv[st][r] - mn);
                    sv[st][r] = p;
                    ps += p;
                }
            ps += __shfl_xor(ps, 16);
            ps += __shfl_xor(ps, 32);
            l = l * corr + ps;
#pragma unroll
            for (int dt = 0; dt < 4; ++dt) {
                accT[dt][0] *= corr; accT[dt][1] *= corr;
                accT[dt][2] *= corr; accT[dt][3] *= corr;
            }
#pragma unroll
            for (int st = 0; st < 4; ++st) {
                f16x4 pk;
                pk[0] = (_Float16)sv[st][0]; pk[1] = (_Float16)sv[st][1];
                pk[2] = (_Float16)sv[st][2]; pk[3] = (_Float16)sv[st][3];
                *(f16x4*)&Pb[w][l15][st * 16 + lg * 4] = pk;
            }
            f16x8 pf0 = *(const f16x8*)&Pb[w][l15][lg * 8];
            f16x8 pf1 = *(const f16x8*)&Pb[w][l15][32 + lg * 8];
            const _Float16* vp = Vt + qkb + (size_t)l15 * SEQ + kt * 64 + lg * 8;
#pragma unroll
            for (int dt = 0; dt < 4; ++dt) {
                f16x8 vb0 = *(const f16x8*)(vp + dt * 16 * SEQ);
                f16x8 vb1 = *(const f16x8*)(vp + dt * 16 * SEQ + 32);
                accT[dt] = __builtin_amdgcn_mfma_f32_16x16x32_f16(vb0, pf0, accT[dt], 0, 0, 0);
                accT[dt] = __builtin_amdgcn_mfma_f32_16x16x32_f16(vb1, pf1, accT[dt], 0, 0, 0);
            }
        }
    };

    f32x4 accA[4], accB[4];
    float mA = -INFINITY, lA = 0.f, mB = -INFINITY, lB = 0.f;
#pragma unroll
    for (int dt = 0; dt < 4; ++dt) {
        accA[dt] = (f32x4){0.f, 0.f, 0.f, 0.f};
        accB[dt] = (f32x4){0.f, 0.f, 0.f, 0.f};
    }

    run(pr, accA, mA, lA);
    run(15 - pr, accB, mB, lB);

    // ---- publish s=1 partials ----
    if (s == 1) {
#pragma unroll
        for (int dt = 0; dt < 4; ++dt) {
            f16x4 pa, pb_;
#pragma unroll
            for (int r = 0; r < 4; ++r) { pa[r] = (_Float16)accA[dt][r]; pb_[r] = (_Float16)accB[dt][r]; }
            *(f16x4*)&part[0][j][ln][dt * 4] = pa;
            *(f16x4*)&part[1][j][ln][dt * 4] = pb_;
        }
        mlb[0][j][ln][0] = mA; mlb[0][j][ln][1] = lA;
        mlb[1][j][ln][0] = mB; mlb[1][j][ln][1] = lB;
    }
    __syncthreads();

    // ---- s=0 merges both jobs and writes ----
    if (s == 0) {
        auto merge = [&](int ji, int qt2, f32x4 (&accT)[4], float m, float l) {
            float m1 = mlb[ji][j][ln][0];
            float l1 = mlb[ji][j][ln][1];
            float mm = fmaxf(m, m1);              // m finite: s=0 split nonempty
            float c0 = __expf(m - mm);
            float c1 = __expf(m1 - mm);           // empty split: exp(-inf)=0
            float li = 1.f / (l * c0 + l1 * c1);
            const int i2 = qt2 * 64 + j * 16 + l15;
            _Float16* aop = ao + ((size_t)(b_ * SEQ + i2)) * DM + h_ * DH + lg * 4;
#pragma unroll
            for (int dt = 0; dt < 4; ++dt) {
                f16x4 o4;
#pragma unroll
                for (int r = 0; r < 4; ++r) {
                    float v = accT[dt][r] * c0 + (float)part[ji][j][ln][dt * 4 + r] * c1;
                    o4[r] = (_Float16)(v * li);
                }
                *(f16x4*)&aop[dt * 16] = o4;
            }
        };
        merge(0, pr, accA, mA, lA);
        merge(1, 15 - pr, accB, mB, lB);
    }
}

// ---------------------------------------------------------------------------
extern "C" void kernel_launch(void* const* d_in, const int* in_sizes, int n_in,
                              void* d_out, int out_size, void* d_ws, size_t ws_size,
                              hipStream_t stream)
{
    (void)in_sizes; (void)n_in; (void)out_size; (void)ws_size;
    const float* x   = (const float*)d_in[0];
    const float* Wq  = (const float*)d_in[1];
    const float* Wk  = (const float*)d_in[2];
    const float* Wv  = (const float*)d_in[3];
    const float* Wo  = (const float*)d_in[4];
    const float* bo  = (const float*)d_in[5];
    const float* rpb = (const float*)d_in[6];
    float* out = (float*)d_out;

    char* ws = (char*)d_ws;
    _Float16* xh  = (_Float16*)(ws);                  // 8 MB
    _Float16* q   = (_Float16*)(ws + (8u  << 20));    // 8 MB
    _Float16* k   = (_Float16*)(ws + (16u << 20));    // 8 MB
    _Float16* v   = (_Float16*)(ws + (24u << 20));    // 8 MB
    _Float16* vt  = (_Float16*)(ws + (32u << 20));    // 8 MB
    _Float16* aoh = (_Float16*)(ws + (40u << 20));    // 8 MB
    _Float16* wqt = (_Float16*)(ws + (48u << 20));    // 2 MB
    _Float16* wkt = (_Float16*)(ws + (50u << 20));    // 2 MB
    _Float16* wvt = (_Float16*)(ws + (52u << 20));    // 2 MB
    _Float16* wot = (_Float16*)(ws + (54u << 20));    // 2 MB

    cvt_x<<<2048, 256, 0, stream>>>(x, xh, BT * DM / 4);
    cvt_wT<<<dim3(16, 16, 4), 256, 0, stream>>>(Wq, Wk, Wv, Wo, wqt, wkt, wvt, wot);
    gemm_mfma<1><<<dim3(24, 32), 256, 0, stream>>>(xh, wqt, wkt, wvt, q, k, v, nullptr);
    vtranspose<<<dim3(SEQ / 64, BATCH * NH), 256, 0, stream>>>(v, vt);
    attn_mfma<<<dim3(8, BATCH * NH), 512, 0, stream>>>(q, k, vt, rpb, aoh);
    gemm_mfma<0><<<dim3(8, 32), 256, 0, stream>>>(aoh, wot, nullptr, nullptr, out, nullptr, nullptr, bo);
}